// Round 4
// baseline (142.816 us; speedup 1.0000x reference)
//
#include <hip/hip_runtime.h>

#define SBD   384
#define NCATS 64
#define EMB   48
#define HT    256
#define HC    128
#define MB    64     // books per block

typedef __attribute__((ext_vector_type(8))) short short8;
typedef __attribute__((ext_vector_type(4))) float f32x4;

__device__ __forceinline__ short f2bf(float x) {
    union { float f; unsigned u; } v; v.f = x;
    unsigned r = v.u + 0x7FFF + ((v.u >> 16) & 1);   // RNE
    return (short)(r >> 16);
}

__device__ __forceinline__ short8 cvt8(float4 a, float4 b) {
    short8 h;
    h[0] = f2bf(a.x); h[1] = f2bf(a.y); h[2] = f2bf(a.z); h[3] = f2bf(a.w);
    h[4] = f2bf(b.x); h[5] = f2bf(b.y); h[6] = f2bf(b.z); h[7] = f2bf(b.w);
    return h;
}

// ---------------------------------------------------------------------------
// Prep: bf16 LINEAR frag images, [n][k] contiguous-k rows (registers, no swz).
// iT1: 12 chunks of [256n][32k] (16KB each); iT2 [48][256]; iC1 [128][64];
// iC2 [48][128].
// ---------------------------------------------------------------------------
__global__ void prep_weights(const float* __restrict__ Wt1, const float* __restrict__ Wt2,
                             const float* __restrict__ Wc1, const float* __restrict__ Wc2,
                             char* __restrict__ iT1, char* __restrict__ iT2,
                             char* __restrict__ iC1, char* __restrict__ iC2) {
    int t = blockIdx.x * blockDim.x + threadIdx.x;
    int stride = gridDim.x * blockDim.x;
    for (int g = t; g < 256 * 48; g += stride) {       // Wt1 [384k][256n]
        int n = g / 48, k0 = (g - n * 48) * 8;
        int c = k0 >> 5, kin = k0 & 31;
        short8 v;
        #pragma unroll
        for (int j = 0; j < 8; ++j) v[j] = f2bf(Wt1[(size_t)(k0 + j) * HT + n]);
        *(short8*)(iT1 + (size_t)c * 16384 + n * 64 + kin * 2) = v;
    }
    for (int g = t; g < 48 * 32; g += stride) {        // Wt2 [256k][48n]
        int n = g / 32, k0 = (g - n * 32) * 8;
        short8 v;
        #pragma unroll
        for (int j = 0; j < 8; ++j) v[j] = f2bf(Wt2[(size_t)(k0 + j) * EMB + n]);
        *(short8*)(iT2 + n * 512 + k0 * 2) = v;
    }
    for (int g = t; g < 128 * 8; g += stride) {        // Wc1 [64k][128n]
        int n = g / 8, k0 = (g - n * 8) * 8;
        short8 v;
        #pragma unroll
        for (int j = 0; j < 8; ++j) v[j] = f2bf(Wc1[(size_t)(k0 + j) * HC + n]);
        *(short8*)(iC1 + n * 128 + k0 * 2) = v;
    }
    for (int g = t; g < 48 * 16; g += stride) {        // Wc2 [128k][48n]
        int n = g / 16, k0 = (g - n * 16) * 8;
        short8 v;
        #pragma unroll
        for (int j = 0; j < 8; ++j) v[j] = f2bf(Wc2[(size_t)(k0 + j) * EMB + n]);
        *(short8*)(iC2 + n * 256 + k0 * 2) = v;
    }
}

// ---------------------------------------------------------------------------
// Encoder. Weights -> registers (L2-resident frag images, prefetch dist 1).
// LDS (64KB, 2 blocks/CU): A dbuf 2x4K @0; H1t 32K @8K; mh 8K @40K; H1c 16K @48K.
// All LDS tiles XOR-swizzled: byte ^= (row&7)<<4.
// Raw s_barrier + lgkmcnt(0) only -- no vmcnt drain (keeps HBM/L2 loads in flight).
// A(sbert) reg-prefetch distance 3; L1 wave grid 2x2 (32 rows x 128 cols/wave).
// ---------------------------------------------------------------------------
__global__ __launch_bounds__(256, 2) void encode_books_mfma(
    const float* __restrict__ sbert, const float* __restrict__ mh,
    const char* __restrict__ iT1, const char* __restrict__ iT2,
    const char* __restrict__ iC1, const char* __restrict__ iC2,
    const float* __restrict__ bt1, const float* __restrict__ bt2,
    const float* __restrict__ bc1, const float* __restrict__ bc2,
    float* __restrict__ E, int nbooks)
{
    __shared__ char lds[65536];

    const int t  = threadIdx.x;
    const int w  = t >> 6;
    const int l  = t & 63;
    const int lr = l & 15;
    const int lg = l >> 4;
    const int book0 = blockIdx.x * MB;
    const int wm = w >> 1, wn = w & 1;      // L1 wave grid 2x2

    // A staging lane map: row = t>>2 (0..63), k0 = (t&3)*8
    const int srow = t >> 2, sk0 = (t & 3) * 8;
    const int sdst = (srow * 64 + sk0 * 2) ^ ((srow & 7) << 4);
    const size_t srb = (size_t)min(book0 + srow, nbooks - 1) * SBD + sk0;

    // L1 B frag base (linear image): ((wn*8+nt)*16+lr)*64 + lg*16
    const char* bb1 = iT1 + wn * 8192 + lr * 64 + lg * 16;

    f32x4 acc[2][8];
    #pragma unroll
    for (int nt = 0; nt < 8; ++nt) {
        float b = bt1[wn * 128 + nt * 16 + lr];
        acc[0][nt] = (f32x4){b, b, b, b};
        acc[1][nt] = (f32x4){b, b, b, b};
    }

    float4 ar[4][2];     // sbert raw ring (dist 3)
    short8 bb[2][8];     // B frag ring (dist 1)

    // ---- prologue: issue A chunks 0..2 + B chunk 0; write A0 ----
    #pragma unroll
    for (int c = 0; c < 3; ++c) {
        const float* p = sbert + srb + c * 32;
        ar[c][0] = *(const float4*)p;
        ar[c][1] = *(const float4*)(p + 4);
    }
    #pragma unroll
    for (int nt = 0; nt < 8; ++nt) bb[0][nt] = *(const short8*)(bb1 + nt * 1024);
    *(short8*)(lds + sdst) = cvt8(ar[0][0], ar[0][1]);
    asm volatile("s_waitcnt lgkmcnt(0)" ::: "memory");
    __builtin_amdgcn_sched_barrier(0);
    __builtin_amdgcn_s_barrier();

    const int ar0 = wm * 32 + lr, ar1 = wm * 32 + 16 + lr;
    const int aoff0 = (ar0 * 64 + lg * 16) ^ ((ar0 & 7) << 4);
    const int aoff1 = (ar1 * 64 + lg * 16) ^ ((ar1 & 7) << 4);

    // ---- L1 txt main loop: 12 chunks, 1 raw barrier/iter, no vmcnt drain ----
    #pragma unroll
    for (int c = 0; c < 12; ++c) {
        if (c + 1 < 12) {
            #pragma unroll
            for (int nt = 0; nt < 8; ++nt)
                bb[(c + 1) & 1][nt] = *(const short8*)(bb1 + (c + 1) * 16384 + nt * 1024);
        }
        if (c + 3 < 12) {
            const float* p = sbert + srb + (c + 3) * 32;
            ar[(c + 3) & 3][0] = *(const float4*)p;
            ar[(c + 3) & 3][1] = *(const float4*)(p + 4);
        }
        if (c + 1 < 12)
            *(short8*)(lds + ((c + 1) & 1) * 4096 + sdst) = cvt8(ar[(c + 1) & 3][0], ar[(c + 1) & 3][1]);
        short8 af0 = *(const short8*)(lds + (c & 1) * 4096 + aoff0);
        short8 af1 = *(const short8*)(lds + (c & 1) * 4096 + aoff1);
        #pragma unroll
        for (int nt = 0; nt < 8; ++nt) {
            acc[0][nt] = __builtin_amdgcn_mfma_f32_16x16x32_bf16(af0, bb[c & 1][nt], acc[0][nt], 0, 0, 0);
            acc[1][nt] = __builtin_amdgcn_mfma_f32_16x16x32_bf16(af1, bb[c & 1][nt], acc[1][nt], 0, 0, 0);
        }
        asm volatile("s_waitcnt lgkmcnt(0)" ::: "memory");
        __builtin_amdgcn_sched_barrier(0);
        __builtin_amdgcn_s_barrier();
    }

    // ---- H1t (relu->bf16->LDS @8K) + mh stage (@40K) ----
    #pragma unroll
    for (int mt = 0; mt < 2; ++mt)
        #pragma unroll
        for (int nt = 0; nt < 8; ++nt)
            #pragma unroll
            for (int r = 0; r < 4; ++r) {
                int row = wm * 32 + mt * 16 + lg * 4 + r;
                int col = wn * 128 + nt * 16 + lr;
                *(unsigned short*)(lds + 8192 + ((row * 512 + col * 2) ^ ((row & 7) << 4))) =
                    (unsigned short)f2bf(fmaxf(acc[mt][nt][r], 0.f));
            }
    #pragma unroll
    for (int i = 0; i < 2; ++i) {
        int g = t + 256 * i;
        int row = g >> 3, k0 = (g & 7) * 8;
        int rb = min(book0 + row, nbooks - 1);
        const float* s = mh + (size_t)rb * NCATS + k0;
        float4 v0 = *(const float4*)s, v1 = *(const float4*)(s + 4);
        *(short8*)(lds + 40960 + ((row * 128 + k0 * 2) ^ ((row & 7) << 4))) = cvt8(v0, v1);
    }
    asm volatile("s_waitcnt lgkmcnt(0)" ::: "memory");
    __builtin_amdgcn_sched_barrier(0);
    __builtin_amdgcn_s_barrier();

    // ---- tail phases: per-wave 16 rows x all cols ----
    const int arow = w * 16 + lr;
    const int aswz = (lr & 7) << 4;

    // L2 txt: H1t[64][256] @ Wt2
    f32x4 acct[3];
    #pragma unroll
    for (int nt = 0; nt < 3; ++nt) { float b = bt2[nt * 16 + lr]; acct[nt] = (f32x4){b, b, b, b}; }
    #pragma unroll
    for (int ks = 0; ks < 8; ++ks) {
        short8 af = *(const short8*)(lds + 8192 + ((arow * 512 + (lg * 8 + ks * 32) * 2) ^ aswz));
        #pragma unroll
        for (int nt = 0; nt < 3; ++nt) {
            short8 bf = *(const short8*)(iT2 + (nt * 16 + lr) * 512 + (lg * 8 + ks * 32) * 2);
            acct[nt] = __builtin_amdgcn_mfma_f32_16x16x32_bf16(af, bf, acct[nt], 0, 0, 0);
        }
    }

    // L1 cat: mh[64][64] @ Wc1
    f32x4 accc[8];
    #pragma unroll
    for (int nt = 0; nt < 8; ++nt) { float b = bc1[nt * 16 + lr]; accc[nt] = (f32x4){b, b, b, b}; }
    #pragma unroll
    for (int ks = 0; ks < 2; ++ks) {
        short8 af = *(const short8*)(lds + 40960 + ((arow * 128 + (lg * 8 + ks * 32) * 2) ^ aswz));
        #pragma unroll
        for (int nt = 0; nt < 8; ++nt) {
            short8 bf = *(const short8*)(iC1 + (nt * 16 + lr) * 128 + (lg * 8 + ks * 32) * 2);
            accc[nt] = __builtin_amdgcn_mfma_f32_16x16x32_bf16(af, bf, accc[nt], 0, 0, 0);
        }
    }
    // H1c -> @48K
    #pragma unroll
    for (int nt = 0; nt < 8; ++nt)
        #pragma unroll
        for (int r = 0; r < 4; ++r) {
            int row = w * 16 + lg * 4 + r, col = nt * 16 + lr;
            *(unsigned short*)(lds + 49152 + ((row * 256 + col * 2) ^ ((row & 7) << 4))) =
                (unsigned short)f2bf(fmaxf(accc[nt][r], 0.f));
        }
    asm volatile("s_waitcnt lgkmcnt(0)" ::: "memory");
    __builtin_amdgcn_sched_barrier(0);
    __builtin_amdgcn_s_barrier();

    // L2 cat: H1c[64][128] @ Wc2
    f32x4 acc2[3];
    #pragma unroll
    for (int nt = 0; nt < 3; ++nt) { float b = bc2[nt * 16 + lr]; acc2[nt] = (f32x4){b, b, b, b}; }
    #pragma unroll
    for (int ks = 0; ks < 4; ++ks) {
        short8 af = *(const short8*)(lds + 49152 + ((arow * 256 + (lg * 8 + ks * 32) * 2) ^ aswz));
        #pragma unroll
        for (int nt = 0; nt < 3; ++nt) {
            short8 bf = *(const short8*)(iC2 + (nt * 16 + lr) * 256 + (lg * 8 + ks * 32) * 2);
            acc2[nt] = __builtin_amdgcn_mfma_f32_16x16x32_bf16(af, bf, acc2[nt], 0, 0, 0);
        }
    }

    // ---- combine, l2norm, store ----
    f32x4 comb[3];
    #pragma unroll
    for (int nt = 0; nt < 3; ++nt)
        #pragma unroll
        for (int r = 0; r < 4; ++r) comb[nt][r] = 3.0f * acc2[nt][r] + acct[nt][r];
    float rn[4];
    #pragma unroll
    for (int r = 0; r < 4; ++r) {
        float ss = comb[0][r] * comb[0][r] + comb[1][r] * comb[1][r] + comb[2][r] * comb[2][r];
        ss += __shfl_xor(ss, 1); ss += __shfl_xor(ss, 2);
        ss += __shfl_xor(ss, 4); ss += __shfl_xor(ss, 8);
        rn[r] = rsqrtf(fmaxf(ss, 1e-12f));
    }
    #pragma unroll
    for (int nt = 0; nt < 3; ++nt)
        #pragma unroll
        for (int r = 0; r < 4; ++r) {
            int grow = book0 + w * 16 + lg * 4 + r;
            if (grow < nbooks) E[(size_t)grow * EMB + nt * 16 + lr] = comb[nt][r] * rn[r];
        }
}

// ---------------------------------------------------------------------------
// Scoring: 16 lanes/sample, 3 dims/lane, shuffle-reduce.
// ---------------------------------------------------------------------------
__global__ __launch_bounds__(256) void score_kernel(
    const int* __restrict__ user_idx, const int* __restrict__ loc_idx,
    const int* __restrict__ pos_idx,  const int* __restrict__ neg_idx,
    const float* __restrict__ ucat, const float* __restrict__ utxt,
    const float* __restrict__ lcat, const float* __restrict__ ltxt,
    const float* __restrict__ E, float* __restrict__ out, int Bn)
{
    const int t    = threadIdx.x;
    const int lane = t & 15;
    const int s    = blockIdx.x * 16 + (t >> 4);
    if (s >= Bn) return;

    const int ui = user_idx[s];
    const int li = loc_idx[s];
    const int pi = pos_idx[s];
    const int ni = neg_idx[s];

    const int d0 = lane * 3;
    const float* uc = ucat + (size_t)ui * EMB + d0;
    const float* ut = utxt + (size_t)ui * EMB + d0;
    const float* lc = lcat + (size_t)li * EMB + d0;
    const float* lt = ltxt + (size_t)li * EMB + d0;
    const float* pp = E + (size_t)pi * EMB + d0;
    const float* nn = E + (size_t)ni * EMB + d0;

    float u0 = 3.0f * (uc[0] + lc[0]) + (ut[0] + lt[0]);
    float u1 = 3.0f * (uc[1] + lc[1]) + (ut[1] + lt[1]);
    float u2 = 3.0f * (uc[2] + lc[2]) + (ut[2] + lt[2]);

    float usq = u0 * u0 + u1 * u1 + u2 * u2;
    float ps  = u0 * pp[0] + u1 * pp[1] + u2 * pp[2];
    float ns  = u0 * nn[0] + u1 * nn[1] + u2 * nn[2];

    #pragma unroll
    for (int m = 1; m < 16; m <<= 1) {
        usq += __shfl_xor(usq, m);
        ps  += __shfl_xor(ps, m);
        ns  += __shfl_xor(ns, m);
    }

    if (lane == 0) {
        const float inv = rsqrtf(fmaxf(usq, 1e-12f)) * 20.0f;  // /TEMP
        out[2 * (size_t)s + 0] = ps * inv;
        out[2 * (size_t)s + 1] = ns * inv;
    }
}

extern "C" void kernel_launch(void* const* d_in, const int* in_sizes, int n_in,
                              void* d_out, int out_size, void* d_ws, size_t ws_size,
                              hipStream_t stream) {
    const int*   user_idx = (const int*)d_in[0];
    const int*   loc_idx  = (const int*)d_in[1];
    const int*   pos_idx  = (const int*)d_in[2];
    const int*   neg_idx  = (const int*)d_in[3];
    const float* ucat     = (const float*)d_in[4];
    const float* utxt     = (const float*)d_in[5];
    const float* lcat     = (const float*)d_in[6];
    const float* ltxt     = (const float*)d_in[7];
    const float* sbert    = (const float*)d_in[8];
    const float* mh       = (const float*)d_in[9];
    const float* Wc1      = (const float*)d_in[10];
    const float* bc1      = (const float*)d_in[11];
    const float* Wc2      = (const float*)d_in[12];
    const float* bc2      = (const float*)d_in[13];
    const float* Wt1      = (const float*)d_in[14];
    const float* bt1      = (const float*)d_in[15];
    const float* Wt2      = (const float*)d_in[16];
    const float* bt2      = (const float*)d_in[17];

    const int Bn     = in_sizes[0];
    const int nbooks = in_sizes[8] / SBD;

    char* ws = (char*)d_ws;
    float* E = (float*)ws;
    size_t off = (size_t)nbooks * EMB * 4;
    off = (off + 255) & ~(size_t)255;
    char* iT1 = ws + off; off += 196608;
    char* iT2 = ws + off; off += 24576;
    char* iC1 = ws + off; off += 16384;
    char* iC2 = ws + off; off += 12288;

    hipLaunchKernelGGL(prep_weights, dim3(64), dim3(256), 0, stream,
                       Wt1, Wt2, Wc1, Wc2, iT1, iT2, iC1, iC2);

    const int nblocksA = (nbooks + MB - 1) / MB;
    hipLaunchKernelGGL(encode_books_mfma, dim3(nblocksA), dim3(256), 0, stream,
                       sbert, mh, iT1, iT2, iC1, iC2, bt1, bt2, bc1, bc2, E, nbooks);

    const int nblocksB = (Bn + 15) / 16;
    hipLaunchKernelGGL(score_kernel, dim3(nblocksB), dim3(256), 0, stream,
                       user_idx, loc_idx, pos_idx, neg_idx,
                       ucat, utxt, lcat, ltxt, E, (float*)d_out, Bn);
}